// Round 1
// 861.260 us; speedup vs baseline: 1.0537x; 1.0537x over previous
//
#include <hip/hip_runtime.h>
#include <math.h>

#define B_ 64
#define P_ 24564
#define C_ 81
#define O_ 20

__device__ __forceinline__ float iou_xy(float ax0, float ay0, float ax1, float ay1,
                                        float bx0, float by0, float bx1, float by1) {
#pragma clang fp contract(off)
    float lx = fmaxf(ax0, bx0), ly = fmaxf(ay0, by0);
    float rx = fminf(ax1, bx1), ry = fminf(ay1, by1);
    float w = fmaxf(rx - lx, 0.f), h = fmaxf(ry - ly, 0.f);
    float inter = w * h;
    float aa = (ax1 - ax0) * (ay1 - ay0);
    float ab = (bx1 - bx0) * (by1 - by0);
    return inter / (aa + ab - inter);
}

__device__ __forceinline__ float sl1(float d) {
#pragma clang fp contract(off)
    float a = fabsf(d);
    return a < 1.f ? 0.5f * a * a : a - 0.5f;
}

// ---- kernel 1: prior_fo[b][o] = argmax_p IoU(box[b,o], prior[p]), first-max.
// Also zeroes the per-batch atomic accumulators (o==0 blocks) so no memset
// dispatch is needed; all consumers launch after this kernel.
__global__ void k_prior(const float* __restrict__ boxes, const float* __restrict__ priors,
                        int* __restrict__ prior_fo, int* __restrict__ n_pos,
                        float* __restrict__ pos_sum, float* __restrict__ tot_sum,
                        float* __restrict__ loc_sum) {
#pragma clang fp contract(off)
    int o = blockIdx.x, b = blockIdx.y, t = threadIdx.x;
    if (o == 0 && t == 0) {
        n_pos[b] = 0; pos_sum[b] = 0.f; tot_sum[b] = 0.f; loc_sum[b] = 0.f;
    }
    const float* bx = boxes + ((size_t)b * O_ + o) * 4;
    float bx0 = bx[0], by0 = bx[1], bx1 = bx[2], by1 = bx[3];
    float best = -1.f;
    int bi = 0;
    for (int p = t; p < P_; p += 256) {
        float4 pr = ((const float4*)priors)[p];
        float px0 = pr.x - pr.z * 0.5f, py0 = pr.y - pr.w * 0.5f;
        float px1 = pr.x + pr.z * 0.5f, py1 = pr.y + pr.w * 0.5f;
        float v = iou_xy(bx0, by0, bx1, by1, px0, py0, px1, py1);
        if (v > best) { best = v; bi = p; }  // strict > keeps first within thread
    }
    __shared__ float sv[256];
    __shared__ int si[256];
    sv[t] = best; si[t] = bi;
    __syncthreads();
    for (int s = 128; s > 0; s >>= 1) {
        if (t < s) {
            float ov = sv[t + s]; int oi = si[t + s];
            if (ov > sv[t] || (ov == sv[t] && oi < si[t])) { sv[t] = ov; si[t] = oi; }
        }
        __syncthreads();
    }
    if (t == 0) prior_fo[b * O_ + o] = si[0];
}

// ---- kernel 2 (fused match + conf): per 64-prior tile, each QUAD of lanes
// owns one prior. The match (argmax over O=20 objects, first-max + prior_fo
// override) runs as pure VALU in the shadow of the 509 MB scores stream that
// the CE part is bound by. Lane q evaluates objects o = q, q+4, ... (5 each);
// a 2-step quad shfl_xor reduce with min-o tiebreak == np.argmax first-max.
// Eliminates the former k_match pass and the true_class round-trip.
// CE math identical to previous k_conf: no max-subtraction (|scores|<~6),
// __expf/__logf, 21/21/21/18 column split, xor-1 then xor-2 combine.
__global__ __launch_bounds__(256) void k_cm(const float* __restrict__ scores,
                                            const float* __restrict__ boxes,
                                            const int* __restrict__ labels,
                                            const float* __restrict__ priors,
                                            const float* __restrict__ plocs,
                                            const int* __restrict__ prior_fo,
                                            float* __restrict__ conf_neg,
                                            float* __restrict__ pos_sum,
                                            float* __restrict__ tot_sum,
                                            float* __restrict__ loc_sum,
                                            int* __restrict__ n_pos) {
#pragma clang fp contract(off)
    __shared__ float4 smem4[1296];  // 64 rows x 81 floats (exact copy of global)
    float* smem = (float*)smem4;
    __shared__ float sb[O_][4];  // xy
    __shared__ float sc[O_][4];  // cxcy
    __shared__ int sl_[O_];
    __shared__ int sf[O_];
    int b = blockIdx.y;
    int p0 = blockIdx.x * 64;
    int t = threadIdx.x, lane = t & 63, w = t >> 6;
    int rows = P_ - p0;
    if (rows > 64) rows = 64;
    int nf4 = rows * 81 / 4;  // rows is 64 or 52, both give exact /4
    const float4* gsrc = (const float4*)(scores + ((size_t)b * P_ + p0) * (size_t)C_);
    for (int i = t; i < nf4; i += 256) smem4[i] = gsrc[i];
    if (t < O_) {
        const float* bx = boxes + ((size_t)b * O_ + t) * 4;
        float x0 = bx[0], y0 = bx[1], x1 = bx[2], y1 = bx[3];
        sb[t][0] = x0; sb[t][1] = y0; sb[t][2] = x1; sb[t][3] = y1;
        sc[t][0] = (x0 + x1) * 0.5f; sc[t][1] = (y0 + y1) * 0.5f;
        sc[t][2] = x1 - x0;          sc[t][3] = y1 - y0;
        sl_[t] = labels[b * O_ + t];
        sf[t] = prior_fo[b * O_ + t];
    }
    __syncthreads();

    int i = t >> 2;    // prior within tile, 0..63
    int q = t & 3;     // quarter of the row / object-strided share
    int p = p0 + i;
    bool active = (i < rows);

    int lab = 0;
    float lsum = 0.f;
    int posc = 0;
    if (active) {
        float4 pr = ((const float4*)priors)[p];
        float px0 = pr.x - pr.z * 0.5f, py0 = pr.y - pr.w * 0.5f;
        float px1 = pr.x + pr.z * 0.5f, py1 = pr.y + pr.w * 0.5f;
        float best = -1.f;
        int bi = 0x7fffffff;
        for (int o = q; o < O_; o += 4) {  // 5 objects per lane
            float v = iou_xy(sb[o][0], sb[o][1], sb[o][2], sb[o][3], px0, py0, px1, py1);
            if (v > best || (v == best && o < bi)) { best = v; bi = o; }
        }
#pragma unroll
        for (int off = 1; off <= 2; off <<= 1) {  // quad reduce, min-o on ties
            float ov = __shfl_xor(best, off);
            int oi = __shfl_xor(bi, off);
            if (ov > best || (ov == best && oi < bi)) { best = ov; bi = oi; }
        }
        // .at[prior_fo].set: ascending o, last match wins (np semantics)
        for (int o = 0; o < O_; o++)
            if (sf[o] == p) { bi = o; best = 1.0f; }
        lab = (best < 0.5f) ? 0 : sl_[bi];
        if (lab != 0 && q == 0) {  // count/encode each prior once
            posc = 1;
            float gx = (sc[bi][0] - pr.x) / (pr.z / 10.0f);
            float gy = (sc[bi][1] - pr.y) / (pr.w / 10.0f);
            float gw = logf(sc[bi][2] / pr.z) * 5.0f;
            float gh = logf(sc[bi][3] / pr.w) * 5.0f;
            float4 pl = ((const float4*)plocs)[(size_t)b * P_ + p];
            lsum = sl1(pl.x - gx) + sl1(pl.y - gy) + sl1(pl.z - gw) + sl1(pl.w - gh);
        }
    }
    int tcv = lab;  // uniform across the quad

    float sum = 0.f, st = 0.f;
    if (active) {
        int base = q * 21;
        int cnt = (q == 3) ? 18 : 21;
        const float* r = smem + i * 81 + base;
        for (int j = 0; j < cnt; j++) {
            float v = r[j];
            sum += __expf(v);
            if (base + j == tcv) st = v;
        }
    }
    sum += __shfl_xor(sum, 1);
    sum += __shfl_xor(sum, 2);
    st += __shfl_xor(st, 1);
    st += __shfl_xor(st, 2);

    float ce = 0.f, posv = 0.f;
    if (active) {
        ce = __logf(sum) - st;
        if (tcv != 0) posv = ce;
        if (q == 0) conf_neg[(size_t)b * P_ + p] = (tcv == 0) ? ce : 0.f;
    }
    // per-thread contributions (count each prior once: q==0 lane only)
    float tc_ = (q == 0) ? ce : 0.f;
    float pc_ = (q == 0) ? posv : 0.f;
    for (int off = 32; off > 0; off >>= 1) {
        tc_ += __shfl_down(tc_, off);
        pc_ += __shfl_down(pc_, off);
        lsum += __shfl_down(lsum, off);
        posc += __shfl_down(posc, off);
    }
    __shared__ float stt[4], spp[4], sll[4];
    __shared__ int snn[4];
    if (lane == 0) { stt[w] = tc_; spp[w] = pc_; sll[w] = lsum; snn[w] = posc; }
    __syncthreads();
    if (t == 0) {
        atomicAdd(&tot_sum[b], stt[0] + stt[1] + stt[2] + stt[3]);
        atomicAdd(&pos_sum[b], spp[0] + spp[1] + spp[2] + spp[3]);
        int n4 = snn[0] + snn[1] + snn[2] + snn[3];
        if (n4 != 0) {
            atomicAdd(&loc_sum[b], sll[0] + sll[1] + sll[2] + sll[3]);
            atomicAdd(&n_pos[b], n4);
        }
    }
}

// ---- kernel 3: exact top-k sum per batch. Whole row lives in registers
// (24 VGPRs x 1024 threads); 31 bisection passes are pure VALU + 1 barrier
// each (fresh LDS counter slot per pass -> no reset barriers).
__global__ __launch_bounds__(1024) void k_topk(const float* __restrict__ conf_neg,
                                               const int* __restrict__ n_pos,
                                               float* __restrict__ hard_sum) {
    int b = blockIdx.x, t = threadIdx.x, lane = t & 63;
    const float* row = conf_neg + (size_t)b * P_;
    unsigned vb[24];
#pragma unroll
    for (int i = 0; i < 24; i++) {
        int p = t + (i << 10);
        vb[i] = (p < P_) ? __float_as_uint(row[p]) : 0u;  // CE>=0 so bits order = value order
    }
    int k = 3 * n_pos[b];
    __shared__ int cnts[32];
    __shared__ float ssum;
    __shared__ int scnt;
    if (k <= 0) {  // uniform across block
        if (t == 0) hard_sum[b] = 0.f;
        return;
    }
    if (t < 32) cnts[t] = 0;
    if (t == 0) { ssum = 0.f; scnt = 0; }
    __syncthreads();
    unsigned lo = 0u, hi = 0x7F800000u;
    int pass = 0;
    while (lo < hi) {  // 31 iterations, uniform
        unsigned mid = lo + ((hi - lo) >> 1);
        int c = 0;
#pragma unroll
        for (int i = 0; i < 24; i++) c += (vb[i] > mid);
        for (int off = 32; off > 0; off >>= 1) c += __shfl_down(c, off);
        if (lane == 0) atomicAdd(&cnts[pass], c);
        __syncthreads();
        int cnt = cnts[pass];
        if (cnt < k) hi = mid; else lo = mid + 1;
        pass++;
    }
    // lo = bits of k-th largest V_k; sum strictly-greater, pad ties at V_k
    float s = 0.f;
    int c = 0;
#pragma unroll
    for (int i = 0; i < 24; i++) {
        if (vb[i] > lo) { s += __uint_as_float(vb[i]); c++; }
    }
    for (int off = 32; off > 0; off >>= 1) {
        s += __shfl_down(s, off);
        c += __shfl_down(c, off);
    }
    if (lane == 0) { atomicAdd(&ssum, s); atomicAdd(&scnt, c); }
    __syncthreads();
    if (t == 0) hard_sum[b] = ssum + (float)(k - scnt) * __uint_as_float(lo);
}

// ---- kernel 4: finalize scalar loss (one wave, lane = batch) ----
__global__ void k_final(const int* __restrict__ n_pos, const float* __restrict__ pos_sum,
                        const float* __restrict__ tot_sum, const float* __restrict__ loc_sum,
                        const float* __restrict__ hard_sum, float* __restrict__ out) {
    int t = threadIdx.x;  // 64 threads == B_
    int np = n_pos[t];
    float ps = pos_sum[t], ts = tot_sum[t], ls = loc_sum[t], hs = hard_sum[t];
    for (int off = 32; off > 0; off >>= 1) {
        np += __shfl_down(np, off);
        ps += __shfl_down(ps, off);
        ts += __shfl_down(ts, off);
        ls += __shfl_down(ls, off);
        hs += __shfl_down(hs, off);
    }
    if (t == 0) {
        float tp = (float)np;
        float conf = (hs + ps) / fmaxf(tp, 1.f);
        float loc = ls / fmaxf(4.f * tp, 1.f);
        float mean = ts / ((float)B_ * (float)P_);
        out[0] = (np > 0) ? (conf + loc) : mean;
    }
}

extern "C" void kernel_launch(void* const* d_in, const int* in_sizes, int n_in,
                              void* d_out, int out_size, void* d_ws, size_t ws_size,
                              hipStream_t stream) {
    const float* plocs  = (const float*)d_in[0];  // [B,P,4]
    const float* scores = (const float*)d_in[1];  // [B,P,C]
    const float* boxes  = (const float*)d_in[2];  // [B,O,4] xy
    const int*   labels = (const int*)d_in[3];    // [B,O]
    const float* priors = (const float*)d_in[4];  // [P,4] cxcy

    char* ws = (char*)d_ws;
    float* conf_neg   = (float*)ws;                              // B*P floats
    int*   prior_fo   = (int*)(ws + (size_t)B_ * P_ * 4);        // B*O ints
    int*   n_pos      = prior_fo + B_ * O_;                      // B ints
    float* pos_sum    = (float*)(n_pos + B_);                    // B floats
    float* tot_sum    = pos_sum + B_;
    float* loc_sum    = tot_sum + B_;
    float* hard_sum   = loc_sum + B_;

    // accumulators zeroed inside k_prior (o==0 blocks); no memset dispatch
    k_prior<<<dim3(O_, B_), 256, 0, stream>>>(boxes, priors, prior_fo,
                                              n_pos, pos_sum, tot_sum, loc_sum);
    k_cm<<<dim3((P_ + 63) / 64, B_), 256, 0, stream>>>(
        scores, boxes, labels, priors, plocs, prior_fo,
        conf_neg, pos_sum, tot_sum, loc_sum, n_pos);
    k_topk<<<B_, 1024, 0, stream>>>(conf_neg, n_pos, hard_sum);
    k_final<<<1, 64, 0, stream>>>(n_pos, pos_sum, tot_sum, loc_sum, hard_sum, (float*)d_out);
}

// Round 2
// 821.458 us; speedup vs baseline: 1.1048x; 1.0485x over previous
//
#include <hip/hip_runtime.h>
#include <math.h>

#define B_ 64
#define P_ 24564
#define C_ 81
#define O_ 20

__device__ __forceinline__ float iou_xy(float ax0, float ay0, float ax1, float ay1,
                                        float bx0, float by0, float bx1, float by1) {
#pragma clang fp contract(off)
    float lx = fmaxf(ax0, bx0), ly = fmaxf(ay0, by0);
    float rx = fminf(ax1, bx1), ry = fminf(ay1, by1);
    float w = fmaxf(rx - lx, 0.f), h = fmaxf(ry - ly, 0.f);
    float inter = w * h;
    float aa = (ax1 - ax0) * (ay1 - ay0);
    float ab = (bx1 - bx0) * (by1 - by0);
    return inter / (aa + ab - inter);
}

__device__ __forceinline__ float sl1(float d) {
#pragma clang fp contract(off)
    float a = fabsf(d);
    return a < 1.f ? 0.5f * a * a : a - 0.5f;
}

// ---- kernel 1: prior_fo[b][o] = argmax_p IoU(box[b,o], prior[p]), first-max.
// Re-decomposed: block (g,b) owns objects 5g..5g+4 and scans priors ONCE
// (was: one block per (b,o) -> 20x redundant priors traffic, 503 MB of L2).
// 256 blocks = 1/CU, 512 threads = 8 waves/CU for L2-latency hiding.
// Also zeroes the per-batch atomic accumulators (g==0 blocks).
__global__ __launch_bounds__(512) void k_prior(const float* __restrict__ boxes,
                                               const float* __restrict__ priors,
                                               int* __restrict__ prior_fo, int* __restrict__ n_pos,
                                               float* __restrict__ pos_sum, float* __restrict__ tot_sum,
                                               float* __restrict__ loc_sum) {
#pragma clang fp contract(off)
    int g = blockIdx.x, b = blockIdx.y, t = threadIdx.x;
    int lane = t & 63, w = t >> 6;
    if (g == 0 && t == 0) {
        n_pos[b] = 0; pos_sum[b] = 0.f; tot_sum[b] = 0.f; loc_sum[b] = 0.f;
    }
    __shared__ float sbx[5][4];
    if (t < 20) ((float*)sbx)[t] = boxes[((size_t)b * O_ + 5 * g) * 4 + t];
    __syncthreads();

    float bv[5];
    int bi[5];
#pragma unroll
    for (int k = 0; k < 5; k++) { bv[k] = -1.f; bi[k] = 0; }

    for (int p = t; p < P_; p += 512) {
        float4 pr = ((const float4*)priors)[p];
        float px0 = pr.x - pr.z * 0.5f, py0 = pr.y - pr.w * 0.5f;
        float px1 = pr.x + pr.z * 0.5f, py1 = pr.y + pr.w * 0.5f;
#pragma unroll
        for (int k = 0; k < 5; k++) {
            float v = iou_xy(sbx[k][0], sbx[k][1], sbx[k][2], sbx[k][3], px0, py0, px1, py1);
            if (v > bv[k]) { bv[k] = v; bi[k] = p; }  // strict > keeps first within thread
        }
    }
    // wave-level argmax per object (first-max: ties -> smaller prior index)
#pragma unroll
    for (int k = 0; k < 5; k++) {
        for (int off = 32; off > 0; off >>= 1) {
            float ov = __shfl_down(bv[k], off);
            int oi = __shfl_down(bi[k], off);
            if (ov > bv[k] || (ov == bv[k] && oi < bi[k])) { bv[k] = ov; bi[k] = oi; }
        }
    }
    __shared__ float swv[8][5];
    __shared__ int swi[8][5];
    if (lane == 0) {
#pragma unroll
        for (int k = 0; k < 5; k++) { swv[w][k] = bv[k]; swi[w][k] = bi[k]; }
    }
    __syncthreads();
    if (t < 5) {
        float best = swv[0][t];
        int besti = swi[0][t];
#pragma unroll
        for (int ww = 1; ww < 8; ww++) {
            float ov = swv[ww][t]; int oi = swi[ww][t];
            if (ov > best || (ov == best && oi < besti)) { best = ov; besti = oi; }
        }
        prior_fo[b * O_ + 5 * g + t] = besti;
    }
}

// ---- kernel 2 (fused match + conf): per 64-prior tile, each QUAD of lanes
// owns one prior. The match (argmax over O=20 objects, first-max + prior_fo
// override) runs as pure VALU in the shadow of the 509 MB scores stream that
// the CE part is bound by. Lane q evaluates objects o = q, q+4, ... (5 each);
// a 2-step quad shfl_xor reduce with min-o tiebreak == np.argmax first-max.
// CE: no max-subtraction (|scores|<~6), __expf/__logf, 21/21/21/18 column
// split, xor-1 then xor-2 combine. Exp loop is UNIFORM 21 iterations fully
// unrolled (compiler pairs ds_read2_b32, hoists loads ahead of the exp
// chain); q==3's phantom 3 terms are discarded by select BEFORE the add
// (+0.0f is exact, so bitwise-identical sum). smem4 padded +1 slot so the
// i=63,q=3,j=19..20 speculative read stays in-bounds (value discarded).
__global__ __launch_bounds__(256) void k_cm(const float* __restrict__ scores,
                                            const float* __restrict__ boxes,
                                            const int* __restrict__ labels,
                                            const float* __restrict__ priors,
                                            const float* __restrict__ plocs,
                                            const int* __restrict__ prior_fo,
                                            float* __restrict__ conf_neg,
                                            float* __restrict__ pos_sum,
                                            float* __restrict__ tot_sum,
                                            float* __restrict__ loc_sum,
                                            int* __restrict__ n_pos) {
#pragma clang fp contract(off)
    __shared__ float4 smem4[1297];  // 64 rows x 81 floats (+1 pad slot)
    float* smem = (float*)smem4;
    __shared__ float sb[O_][4];  // xy
    __shared__ float sc[O_][4];  // cxcy
    __shared__ int sl_[O_];
    __shared__ int sf[O_];
    int b = blockIdx.y;
    int p0 = blockIdx.x * 64;
    int t = threadIdx.x, lane = t & 63, w = t >> 6;
    int rows = P_ - p0;
    if (rows > 64) rows = 64;
    const float4* gsrc = (const float4*)(scores + ((size_t)b * P_ + p0) * (size_t)C_);
    if (rows == 64) {  // full tile: 1296 float4 = 5 whole strides + 16 tail
#pragma unroll
        for (int u = 0; u < 5; u++) smem4[t + u * 256] = gsrc[t + u * 256];
        if (t < 16) smem4[t + 1280] = gsrc[t + 1280];
    } else {
        int nf4 = rows * 81 / 4;  // rows=52 -> exact /4
        for (int i = t; i < nf4; i += 256) smem4[i] = gsrc[i];
    }
    if (t < O_) {
        const float* bx = boxes + ((size_t)b * O_ + t) * 4;
        float x0 = bx[0], y0 = bx[1], x1 = bx[2], y1 = bx[3];
        sb[t][0] = x0; sb[t][1] = y0; sb[t][2] = x1; sb[t][3] = y1;
        sc[t][0] = (x0 + x1) * 0.5f; sc[t][1] = (y0 + y1) * 0.5f;
        sc[t][2] = x1 - x0;          sc[t][3] = y1 - y0;
        sl_[t] = labels[b * O_ + t];
        sf[t] = prior_fo[b * O_ + t];
    }
    __syncthreads();

    int i = t >> 2;    // prior within tile, 0..63
    int q = t & 3;     // quarter of the row / object-strided share
    int p = p0 + i;
    bool active = (i < rows);

    int lab = 0;
    float lsum = 0.f;
    int posc = 0;
    if (active) {
        float4 pr = ((const float4*)priors)[p];
        float px0 = pr.x - pr.z * 0.5f, py0 = pr.y - pr.w * 0.5f;
        float px1 = pr.x + pr.z * 0.5f, py1 = pr.y + pr.w * 0.5f;
        float best = -1.f;
        int bi = 0x7fffffff;
#pragma unroll
        for (int o = q; o < O_; o += 4) {  // 5 objects per lane
            float v = iou_xy(sb[o][0], sb[o][1], sb[o][2], sb[o][3], px0, py0, px1, py1);
            if (v > best || (v == best && o < bi)) { best = v; bi = o; }
        }
#pragma unroll
        for (int off = 1; off <= 2; off <<= 1) {  // quad reduce, min-o on ties
            float ov = __shfl_xor(best, off);
            int oi = __shfl_xor(bi, off);
            if (ov > best || (ov == best && oi < bi)) { best = ov; bi = oi; }
        }
        // .at[prior_fo].set: ascending o, last match wins (np semantics)
#pragma unroll
        for (int o = 0; o < O_; o++)
            if (sf[o] == p) { bi = o; best = 1.0f; }
        lab = (best < 0.5f) ? 0 : sl_[bi];
        if (lab != 0 && q == 0) {  // count/encode each prior once
            posc = 1;
            float gx = (sc[bi][0] - pr.x) / (pr.z / 10.0f);
            float gy = (sc[bi][1] - pr.y) / (pr.w / 10.0f);
            float gw = logf(sc[bi][2] / pr.z) * 5.0f;
            float gh = logf(sc[bi][3] / pr.w) * 5.0f;
            float4 pl = ((const float4*)plocs)[(size_t)b * P_ + p];
            lsum = sl1(pl.x - gx) + sl1(pl.y - gy) + sl1(pl.z - gw) + sl1(pl.w - gh);
        }
    }
    int tcv = lab;  // uniform across the quad

    float sum = 0.f, st = 0.f;
    if (active) {
        int base = q * 21;
        int cnt = (q == 3) ? 18 : 21;
        const float* r = smem + i * 81 + base;
#pragma unroll
        for (int j = 0; j < 21; j++) {
            float v = r[j];                   // j>=cnt: speculative, discarded
            float e = __expf(v);
            sum += (j < cnt) ? e : 0.f;       // +0.0f exact for phantom lanes
            if (base + j == tcv) st = v;      // base+j>=81>tcv when j>=cnt: auto-safe
        }
    }
    sum += __shfl_xor(sum, 1);
    sum += __shfl_xor(sum, 2);
    st += __shfl_xor(st, 1);
    st += __shfl_xor(st, 2);

    float ce = 0.f, posv = 0.f;
    if (active) {
        ce = __logf(sum) - st;
        if (tcv != 0) posv = ce;
        if (q == 0) conf_neg[(size_t)b * P_ + p] = (tcv == 0) ? ce : 0.f;
    }
    // per-thread contributions (count each prior once: q==0 lane only)
    float tc_ = (q == 0) ? ce : 0.f;
    float pc_ = (q == 0) ? posv : 0.f;
    for (int off = 32; off > 0; off >>= 1) {
        tc_ += __shfl_down(tc_, off);
        pc_ += __shfl_down(pc_, off);
        lsum += __shfl_down(lsum, off);
        posc += __shfl_down(posc, off);
    }
    __shared__ float stt[4], spp[4], sll[4];
    __shared__ int snn[4];
    if (lane == 0) { stt[w] = tc_; spp[w] = pc_; sll[w] = lsum; snn[w] = posc; }
    __syncthreads();
    if (t == 0) {
        atomicAdd(&tot_sum[b], stt[0] + stt[1] + stt[2] + stt[3]);
        atomicAdd(&pos_sum[b], spp[0] + spp[1] + spp[2] + spp[3]);
        int n4 = snn[0] + snn[1] + snn[2] + snn[3];
        if (n4 != 0) {
            atomicAdd(&loc_sum[b], sll[0] + sll[1] + sll[2] + sll[3]);
            atomicAdd(&n_pos[b], n4);
        }
    }
}

// ---- kernel 3: exact top-k sum per batch. Whole row lives in registers
// (24 VGPRs x 1024 threads); 31 bisection passes are pure VALU + 1 barrier
// each (fresh LDS counter slot per pass -> no reset barriers).
__global__ __launch_bounds__(1024) void k_topk(const float* __restrict__ conf_neg,
                                               const int* __restrict__ n_pos,
                                               float* __restrict__ hard_sum) {
    int b = blockIdx.x, t = threadIdx.x, lane = t & 63;
    const float* row = conf_neg + (size_t)b * P_;
    unsigned vb[24];
#pragma unroll
    for (int i = 0; i < 24; i++) {
        int p = t + (i << 10);
        vb[i] = (p < P_) ? __float_as_uint(row[p]) : 0u;  // CE>=0 so bits order = value order
    }
    int k = 3 * n_pos[b];
    __shared__ int cnts[32];
    __shared__ float ssum;
    __shared__ int scnt;
    if (k <= 0) {  // uniform across block
        if (t == 0) hard_sum[b] = 0.f;
        return;
    }
    if (t < 32) cnts[t] = 0;
    if (t == 0) { ssum = 0.f; scnt = 0; }
    __syncthreads();
    unsigned lo = 0u, hi = 0x7F800000u;
    int pass = 0;
    while (lo < hi) {  // 31 iterations, uniform
        unsigned mid = lo + ((hi - lo) >> 1);
        int c = 0;
#pragma unroll
        for (int i = 0; i < 24; i++) c += (vb[i] > mid);
        for (int off = 32; off > 0; off >>= 1) c += __shfl_down(c, off);
        if (lane == 0) atomicAdd(&cnts[pass], c);
        __syncthreads();
        int cnt = cnts[pass];
        if (cnt < k) hi = mid; else lo = mid + 1;
        pass++;
    }
    // lo = bits of k-th largest V_k; sum strictly-greater, pad ties at V_k
    float s = 0.f;
    int c = 0;
#pragma unroll
    for (int i = 0; i < 24; i++) {
        if (vb[i] > lo) { s += __uint_as_float(vb[i]); c++; }
    }
    for (int off = 32; off > 0; off >>= 1) {
        s += __shfl_down(s, off);
        c += __shfl_down(c, off);
    }
    if (lane == 0) { atomicAdd(&ssum, s); atomicAdd(&scnt, c); }
    __syncthreads();
    if (t == 0) hard_sum[b] = ssum + (float)(k - scnt) * __uint_as_float(lo);
}

// ---- kernel 4: finalize scalar loss (one wave, lane = batch) ----
__global__ void k_final(const int* __restrict__ n_pos, const float* __restrict__ pos_sum,
                        const float* __restrict__ tot_sum, const float* __restrict__ loc_sum,
                        const float* __restrict__ hard_sum, float* __restrict__ out) {
    int t = threadIdx.x;  // 64 threads == B_
    int np = n_pos[t];
    float ps = pos_sum[t], ts = tot_sum[t], ls = loc_sum[t], hs = hard_sum[t];
    for (int off = 32; off > 0; off >>= 1) {
        np += __shfl_down(np, off);
        ps += __shfl_down(ps, off);
        ts += __shfl_down(ts, off);
        ls += __shfl_down(ls, off);
        hs += __shfl_down(hs, off);
    }
    if (t == 0) {
        float tp = (float)np;
        float conf = (hs + ps) / fmaxf(tp, 1.f);
        float loc = ls / fmaxf(4.f * tp, 1.f);
        float mean = ts / ((float)B_ * (float)P_);
        out[0] = (np > 0) ? (conf + loc) : mean;
    }
}

extern "C" void kernel_launch(void* const* d_in, const int* in_sizes, int n_in,
                              void* d_out, int out_size, void* d_ws, size_t ws_size,
                              hipStream_t stream) {
    const float* plocs  = (const float*)d_in[0];  // [B,P,4]
    const float* scores = (const float*)d_in[1];  // [B,P,C]
    const float* boxes  = (const float*)d_in[2];  // [B,O,4] xy
    const int*   labels = (const int*)d_in[3];    // [B,O]
    const float* priors = (const float*)d_in[4];  // [P,4] cxcy

    char* ws = (char*)d_ws;
    float* conf_neg   = (float*)ws;                              // B*P floats
    int*   prior_fo   = (int*)(ws + (size_t)B_ * P_ * 4);        // B*O ints
    int*   n_pos      = prior_fo + B_ * O_;                      // B ints
    float* pos_sum    = (float*)(n_pos + B_);                    // B floats
    float* tot_sum    = pos_sum + B_;
    float* loc_sum    = tot_sum + B_;
    float* hard_sum   = loc_sum + B_;

    // accumulators zeroed inside k_prior (g==0 blocks); no memset dispatch
    k_prior<<<dim3(4, B_), 512, 0, stream>>>(boxes, priors, prior_fo,
                                             n_pos, pos_sum, tot_sum, loc_sum);
    k_cm<<<dim3((P_ + 63) / 64, B_), 256, 0, stream>>>(
        scores, boxes, labels, priors, plocs, prior_fo,
        conf_neg, pos_sum, tot_sum, loc_sum, n_pos);
    k_topk<<<B_, 1024, 0, stream>>>(conf_neg, n_pos, hard_sum);
    k_final<<<1, 64, 0, stream>>>(n_pos, pos_sum, tot_sum, loc_sum, hard_sum, (float*)d_out);
}

// Round 3
// 820.243 us; speedup vs baseline: 1.1064x; 1.0015x over previous
//
#include <hip/hip_runtime.h>
#include <math.h>

#define B_ 64
#define P_ 24564
#define C_ 81
#define O_ 20

__device__ __forceinline__ float iou_xy(float ax0, float ay0, float ax1, float ay1,
                                        float bx0, float by0, float bx1, float by1) {
#pragma clang fp contract(off)
    float lx = fmaxf(ax0, bx0), ly = fmaxf(ay0, by0);
    float rx = fminf(ax1, bx1), ry = fminf(ay1, by1);
    float w = fmaxf(rx - lx, 0.f), h = fmaxf(ry - ly, 0.f);
    float inter = w * h;
    float aa = (ax1 - ax0) * (ay1 - ay0);
    float ab = (bx1 - bx0) * (by1 - by0);
    return inter / (aa + ab - inter);
}

__device__ __forceinline__ float sl1(float d) {
#pragma clang fp contract(off)
    float a = fabsf(d);
    return a < 1.f ? 0.5f * a * a : a - 0.5f;
}

// ---- kernel 1: prior_fo[b][o] = argmax_p IoU(box[b,o], prior[p]), first-max.
// Block (g,b) owns objects 5g..5g+4 and scans priors ONCE. 256 blocks = 1/CU,
// 512 threads = 8 waves/CU for L2-latency hiding. Also zeroes the per-batch
// atomic accumulators (g==0 blocks) and the grid done-counter (g==0,b==0).
__global__ __launch_bounds__(512) void k_prior(const float* __restrict__ boxes,
                                               const float* __restrict__ priors,
                                               int* __restrict__ prior_fo, int* __restrict__ n_pos,
                                               float* __restrict__ pos_sum, float* __restrict__ tot_sum,
                                               float* __restrict__ loc_sum, int* __restrict__ done) {
#pragma clang fp contract(off)
    int g = blockIdx.x, b = blockIdx.y, t = threadIdx.x;
    int lane = t & 63, w = t >> 6;
    if (g == 0 && t == 0) {
        n_pos[b] = 0; pos_sum[b] = 0.f; tot_sum[b] = 0.f; loc_sum[b] = 0.f;
        if (b == 0) *done = 0;
    }
    __shared__ float sbx[5][4];
    if (t < 20) ((float*)sbx)[t] = boxes[((size_t)b * O_ + 5 * g) * 4 + t];
    __syncthreads();

    float bv[5];
    int bi[5];
#pragma unroll
    for (int k = 0; k < 5; k++) { bv[k] = -1.f; bi[k] = 0; }

    for (int p = t; p < P_; p += 512) {
        float4 pr = ((const float4*)priors)[p];
        float px0 = pr.x - pr.z * 0.5f, py0 = pr.y - pr.w * 0.5f;
        float px1 = pr.x + pr.z * 0.5f, py1 = pr.y + pr.w * 0.5f;
#pragma unroll
        for (int k = 0; k < 5; k++) {
            float v = iou_xy(sbx[k][0], sbx[k][1], sbx[k][2], sbx[k][3], px0, py0, px1, py1);
            if (v > bv[k]) { bv[k] = v; bi[k] = p; }  // strict > keeps first within thread
        }
    }
    // wave-level argmax per object (first-max: ties -> smaller prior index)
#pragma unroll
    for (int k = 0; k < 5; k++) {
        for (int off = 32; off > 0; off >>= 1) {
            float ov = __shfl_down(bv[k], off);
            int oi = __shfl_down(bi[k], off);
            if (ov > bv[k] || (ov == bv[k] && oi < bi[k])) { bv[k] = ov; bi[k] = oi; }
        }
    }
    __shared__ float swv[8][5];
    __shared__ int swi[8][5];
    if (lane == 0) {
#pragma unroll
        for (int k = 0; k < 5; k++) { swv[w][k] = bv[k]; swi[w][k] = bi[k]; }
    }
    __syncthreads();
    if (t < 5) {
        float best = swv[0][t];
        int besti = swi[0][t];
#pragma unroll
        for (int ww = 1; ww < 8; ww++) {
            float ov = swv[ww][t]; int oi = swi[ww][t];
            if (ov > best || (ov == best && oi < besti)) { best = ov; besti = oi; }
        }
        prior_fo[b * O_ + 5 * g + t] = besti;
    }
}

// ---- kernel 2 (fused match + conf): per 64-prior tile, each QUAD of lanes
// owns one prior. The match (argmax over O=20 objects, first-max + prior_fo
// override) runs as pure VALU in the shadow of the 509 MB scores stream that
// the CE part is bound by. Lane q evaluates objects o = q, q+4, ... (5 each);
// a 2-step quad shfl_xor reduce with min-o tiebreak == np.argmax first-max.
// CE: no max-subtraction (|scores|<~6), __expf/__logf, 21/21/21/18 column
// split, xor-1 then xor-2 combine. Exp loop is UNIFORM 21 iterations fully
// unrolled; q==3's phantom 3 terms are discarded by select BEFORE the add
// (+0.0f is exact, so bitwise-identical sum). smem4 padded +1 slot so the
// i=63,q=3,j=19..20 speculative read stays in-bounds (value discarded).
__global__ __launch_bounds__(256) void k_cm(const float* __restrict__ scores,
                                            const float* __restrict__ boxes,
                                            const int* __restrict__ labels,
                                            const float* __restrict__ priors,
                                            const float* __restrict__ plocs,
                                            const int* __restrict__ prior_fo,
                                            float* __restrict__ conf_neg,
                                            float* __restrict__ pos_sum,
                                            float* __restrict__ tot_sum,
                                            float* __restrict__ loc_sum,
                                            int* __restrict__ n_pos) {
#pragma clang fp contract(off)
    __shared__ float4 smem4[1297];  // 64 rows x 81 floats (+1 pad slot)
    float* smem = (float*)smem4;
    __shared__ float sb[O_][4];  // xy
    __shared__ float sc[O_][4];  // cxcy
    __shared__ int sl_[O_];
    __shared__ int sf[O_];
    int b = blockIdx.y;
    int p0 = blockIdx.x * 64;
    int t = threadIdx.x, lane = t & 63, w = t >> 6;
    int rows = P_ - p0;
    if (rows > 64) rows = 64;
    const float4* gsrc = (const float4*)(scores + ((size_t)b * P_ + p0) * (size_t)C_);
    if (rows == 64) {  // full tile: 1296 float4 = 5 whole strides + 16 tail
#pragma unroll
        for (int u = 0; u < 5; u++) smem4[t + u * 256] = gsrc[t + u * 256];
        if (t < 16) smem4[t + 1280] = gsrc[t + 1280];
    } else {
        int nf4 = rows * 81 / 4;  // rows=52 -> exact /4
        for (int i = t; i < nf4; i += 256) smem4[i] = gsrc[i];
    }
    if (t < O_) {
        const float* bx = boxes + ((size_t)b * O_ + t) * 4;
        float x0 = bx[0], y0 = bx[1], x1 = bx[2], y1 = bx[3];
        sb[t][0] = x0; sb[t][1] = y0; sb[t][2] = x1; sb[t][3] = y1;
        sc[t][0] = (x0 + x1) * 0.5f; sc[t][1] = (y0 + y1) * 0.5f;
        sc[t][2] = x1 - x0;          sc[t][3] = y1 - y0;
        sl_[t] = labels[b * O_ + t];
        sf[t] = prior_fo[b * O_ + t];
    }
    __syncthreads();

    int i = t >> 2;    // prior within tile, 0..63
    int q = t & 3;     // quarter of the row / object-strided share
    int p = p0 + i;
    bool active = (i < rows);

    int lab = 0;
    float lsum = 0.f;
    int posc = 0;
    if (active) {
        float4 pr = ((const float4*)priors)[p];
        float px0 = pr.x - pr.z * 0.5f, py0 = pr.y - pr.w * 0.5f;
        float px1 = pr.x + pr.z * 0.5f, py1 = pr.y + pr.w * 0.5f;
        float best = -1.f;
        int bi = 0x7fffffff;
#pragma unroll
        for (int o = q; o < O_; o += 4) {  // 5 objects per lane
            float v = iou_xy(sb[o][0], sb[o][1], sb[o][2], sb[o][3], px0, py0, px1, py1);
            if (v > best || (v == best && o < bi)) { best = v; bi = o; }
        }
#pragma unroll
        for (int off = 1; off <= 2; off <<= 1) {  // quad reduce, min-o on ties
            float ov = __shfl_xor(best, off);
            int oi = __shfl_xor(bi, off);
            if (ov > best || (ov == best && oi < bi)) { best = ov; bi = oi; }
        }
        // .at[prior_fo].set: ascending o, last match wins (np semantics)
#pragma unroll
        for (int o = 0; o < O_; o++)
            if (sf[o] == p) { bi = o; best = 1.0f; }
        lab = (best < 0.5f) ? 0 : sl_[bi];
        if (lab != 0 && q == 0) {  // count/encode each prior once
            posc = 1;
            float gx = (sc[bi][0] - pr.x) / (pr.z / 10.0f);
            float gy = (sc[bi][1] - pr.y) / (pr.w / 10.0f);
            float gw = logf(sc[bi][2] / pr.z) * 5.0f;
            float gh = logf(sc[bi][3] / pr.w) * 5.0f;
            float4 pl = ((const float4*)plocs)[(size_t)b * P_ + p];
            lsum = sl1(pl.x - gx) + sl1(pl.y - gy) + sl1(pl.z - gw) + sl1(pl.w - gh);
        }
    }
    int tcv = lab;  // uniform across the quad

    float sum = 0.f, st = 0.f;
    if (active) {
        int base = q * 21;
        int cnt = (q == 3) ? 18 : 21;
        const float* r = smem + i * 81 + base;
#pragma unroll
        for (int j = 0; j < 21; j++) {
            float v = r[j];                   // j>=cnt: speculative, discarded
            float e = __expf(v);
            sum += (j < cnt) ? e : 0.f;       // +0.0f exact for phantom lanes
            if (base + j == tcv) st = v;      // base+j>=81>tcv when j>=cnt: auto-safe
        }
    }
    sum += __shfl_xor(sum, 1);
    sum += __shfl_xor(sum, 2);
    st += __shfl_xor(st, 1);
    st += __shfl_xor(st, 2);

    float ce = 0.f, posv = 0.f;
    if (active) {
        ce = __logf(sum) - st;
        if (tcv != 0) posv = ce;
        if (q == 0) conf_neg[(size_t)b * P_ + p] = (tcv == 0) ? ce : 0.f;
    }
    // per-thread contributions (count each prior once: q==0 lane only)
    float tc_ = (q == 0) ? ce : 0.f;
    float pc_ = (q == 0) ? posv : 0.f;
    for (int off = 32; off > 0; off >>= 1) {
        tc_ += __shfl_down(tc_, off);
        pc_ += __shfl_down(pc_, off);
        lsum += __shfl_down(lsum, off);
        posc += __shfl_down(posc, off);
    }
    __shared__ float stt[4], spp[4], sll[4];
    __shared__ int snn[4];
    if (lane == 0) { stt[w] = tc_; spp[w] = pc_; sll[w] = lsum; snn[w] = posc; }
    __syncthreads();
    if (t == 0) {
        atomicAdd(&tot_sum[b], stt[0] + stt[1] + stt[2] + stt[3]);
        atomicAdd(&pos_sum[b], spp[0] + spp[1] + spp[2] + spp[3]);
        int n4 = snn[0] + snn[1] + snn[2] + snn[3];
        if (n4 != 0) {
            atomicAdd(&loc_sum[b], sll[0] + sll[1] + sll[2] + sll[3]);
            atomicAdd(&n_pos[b], n4);
        }
    }
}

// ---- kernel 3: exact top-k sum per batch + fused finalization.
// Whole row lives in registers (24 VGPRs x 1024 threads, loaded as float4);
// 31 bisection passes are pure VALU + 1 barrier each (fresh LDS counter slot
// per pass -> no reset barriers). The LAST block to finish (device-scope
// done-counter) reduces the 64 per-batch scalars and writes the loss --
// scoped __hip_atomic_* ops handle cross-XCD L2 non-coherence.
__global__ __launch_bounds__(1024) void k_topk(const float* __restrict__ conf_neg,
                                               const int* __restrict__ n_pos,
                                               const float* __restrict__ pos_sum,
                                               const float* __restrict__ tot_sum,
                                               const float* __restrict__ loc_sum,
                                               float* __restrict__ hard_sum,
                                               int* __restrict__ done,
                                               float* __restrict__ out) {
    int b = blockIdx.x, t = threadIdx.x, lane = t & 63;
    const float4* row4 = (const float4*)(conf_neg + (size_t)b * P_);
    unsigned vb[24];
#pragma unroll
    for (int i = 0; i < 6; i++) {
        int j = t + (i << 10);                      // float4 index; P_/4 = 6141 exact
        float4 v4 = make_float4(0.f, 0.f, 0.f, 0.f);
        if (j < P_ / 4) v4 = row4[j];               // CE>=0 so bits order = value order
        vb[4 * i + 0] = __float_as_uint(v4.x);
        vb[4 * i + 1] = __float_as_uint(v4.y);
        vb[4 * i + 2] = __float_as_uint(v4.z);
        vb[4 * i + 3] = __float_as_uint(v4.w);
    }
    int k = 3 * n_pos[b];  // uniform per block
    __shared__ int cnts[32];
    __shared__ float ssum;
    __shared__ int scnt;
    __shared__ int sold;
    float result = 0.f;  // valid on t==0
    if (k > 0) {  // block-uniform branch: barriers inside are safe
        if (t < 32) cnts[t] = 0;
        if (t == 0) { ssum = 0.f; scnt = 0; }
        __syncthreads();
        unsigned lo = 0u, hi = 0x7F800000u;
        int pass = 0;
        while (lo < hi) {  // 31 iterations, uniform
            unsigned mid = lo + ((hi - lo) >> 1);
            int c = 0;
#pragma unroll
            for (int i = 0; i < 24; i++) c += (vb[i] > mid);
            for (int off = 32; off > 0; off >>= 1) c += __shfl_down(c, off);
            if (lane == 0) atomicAdd(&cnts[pass], c);
            __syncthreads();
            int cnt = cnts[pass];
            if (cnt < k) hi = mid; else lo = mid + 1;
            pass++;
        }
        // lo = bits of k-th largest V_k; sum strictly-greater, pad ties at V_k
        float s = 0.f;
        int c = 0;
#pragma unroll
        for (int i = 0; i < 24; i++) {
            if (vb[i] > lo) { s += __uint_as_float(vb[i]); c++; }
        }
        for (int off = 32; off > 0; off >>= 1) {
            s += __shfl_down(s, off);
            c += __shfl_down(c, off);
        }
        if (lane == 0) { atomicAdd(&ssum, s); atomicAdd(&scnt, c); }
        __syncthreads();
        if (t == 0) result = ssum + (float)(k - scnt) * __uint_as_float(lo);
    }
    // ---- fused finalization: last block reduces the per-batch scalars ----
    if (t == 0) {
        __hip_atomic_store(&hard_sum[b], result, __ATOMIC_RELEASE, __HIP_MEMORY_SCOPE_AGENT);
        sold = __hip_atomic_fetch_add(done, 1, __ATOMIC_ACQ_REL, __HIP_MEMORY_SCOPE_AGENT);
    }
    __syncthreads();
    if (sold == B_ - 1 && t < 64) {  // we are the last block; wave 0 finalizes
        int np = n_pos[t];
        float ps = pos_sum[t], ts = tot_sum[t], ls = loc_sum[t];
        float hs = __hip_atomic_load(&hard_sum[t], __ATOMIC_ACQUIRE, __HIP_MEMORY_SCOPE_AGENT);
        for (int off = 32; off > 0; off >>= 1) {
            np += __shfl_down(np, off);
            ps += __shfl_down(ps, off);
            ts += __shfl_down(ts, off);
            ls += __shfl_down(ls, off);
            hs += __shfl_down(hs, off);
        }
        if (t == 0) {
            float tp = (float)np;
            float conf = (hs + ps) / fmaxf(tp, 1.f);
            float loc = ls / fmaxf(4.f * tp, 1.f);
            float mean = ts / ((float)B_ * (float)P_);
            out[0] = (np > 0) ? (conf + loc) : mean;
        }
    }
}

extern "C" void kernel_launch(void* const* d_in, const int* in_sizes, int n_in,
                              void* d_out, int out_size, void* d_ws, size_t ws_size,
                              hipStream_t stream) {
    const float* plocs  = (const float*)d_in[0];  // [B,P,4]
    const float* scores = (const float*)d_in[1];  // [B,P,C]
    const float* boxes  = (const float*)d_in[2];  // [B,O,4] xy
    const int*   labels = (const int*)d_in[3];    // [B,O]
    const float* priors = (const float*)d_in[4];  // [P,4] cxcy

    char* ws = (char*)d_ws;
    float* conf_neg   = (float*)ws;                              // B*P floats
    int*   prior_fo   = (int*)(ws + (size_t)B_ * P_ * 4);        // B*O ints
    int*   n_pos      = prior_fo + B_ * O_;                      // B ints
    float* pos_sum    = (float*)(n_pos + B_);                    // B floats
    float* tot_sum    = pos_sum + B_;
    float* loc_sum    = tot_sum + B_;
    float* hard_sum   = loc_sum + B_;
    int*   done       = (int*)(hard_sum + B_);                   // 1 int

    // accumulators + done zeroed inside k_prior; no memset dispatch
    k_prior<<<dim3(4, B_), 512, 0, stream>>>(boxes, priors, prior_fo,
                                             n_pos, pos_sum, tot_sum, loc_sum, done);
    k_cm<<<dim3((P_ + 63) / 64, B_), 256, 0, stream>>>(
        scores, boxes, labels, priors, plocs, prior_fo,
        conf_neg, pos_sum, tot_sum, loc_sum, n_pos);
    k_topk<<<B_, 1024, 0, stream>>>(conf_neg, n_pos, pos_sum, tot_sum, loc_sum,
                                    hard_sum, done, (float*)d_out);
}